// Round 1
// baseline (641.823 us; speedup 1.0000x reference)
//
#include <hip/hip_runtime.h>
#include <cstddef>

#define B_    4
#define CIN_  256
#define COUT_ 256
#define H_    64
#define W_    64
#define K_    3
#define KK_   9
#define G_    4
#define PAD_  1
#define TP    32   // pixels per block (half a W-row)

// Pre-transpose weights: wT[kk][c][o] = w[o][c][kk]  (makes LDS staging coalesced)
__global__ __launch_bounds__(256) void wt_kernel(const float* __restrict__ w,
                                                 float* __restrict__ wT) {
    int idx = blockIdx.x * 256 + threadIdx.x;
    if (idx >= KK_ * CIN_ * COUT_) return;
    int o    = idx % COUT_;
    int rest = idx / COUT_;
    int c    = rest % CIN_;
    int kk   = rest / CIN_;
    wT[idx] = w[(o * CIN_ + c) * KK_ + kk];
}

__global__ __launch_bounds__(256) void dcn_kernel(
    const float* __restrict__ x, const float* __restrict__ y,
    const float* __restrict__ w_off, const float* __restrict__ wT,
    float* __restrict__ out)
{
    __shared__ float s_samp[CIN_][TP];          // 32 KB: sampled values for current tap
    __shared__ float s_w[32][COUT_];            // 32 KB: weight chunk [ci][o]
    __shared__ float s_off[G_][KK_][2][TP];     //  9 KB: dy/dx per (group, tap, pixel)

    const int tid = threadIdx.x;
    const int b   = blockIdx.z;
    const int h   = blockIdx.y;
    const int w0  = blockIdx.x * TP;

    // ---- offsets: off[ch] = y0*w_off[ch][0] + y1*w_off[ch][1], ch=(g*KK+kk)*2+d ----
    for (int i = tid; i < G_ * KK_ * 2 * TP; i += 256) {
        int p  = i & (TP - 1);
        int r  = i / TP;
        int d  = r & 1;
        int gk = r >> 1;              // g*KK_ + kk
        int kk = gk % KK_;
        int g  = gk / KK_;
        int ch = gk * 2 + d;
        float yv0 = y[((b * 2 + 0) * H_ + h) * W_ + w0 + p];
        float yv1 = y[((b * 2 + 1) * H_ + h) * W_ + w0 + p];
        s_off[g][kk][d][p] = yv0 * w_off[ch * 2 + 0] + yv1 * w_off[ch * 2 + 1];
    }

    const int p    = tid & (TP - 1);  // pixel lane for sampling
    const int crow = tid >> 5;        // channel row for sampling (0..7)
    const int o0   = (tid >> 3) << 3; // gemm: 8 output channels per thread
    const int p0   = (tid & 7) << 2;  // gemm: 4 pixels per thread

    float acc[8][4];
    #pragma unroll
    for (int i = 0; i < 8; ++i)
        #pragma unroll
        for (int j = 0; j < 4; ++j) acc[i][j] = 0.f;

    for (int kk = 0; kk < KK_; ++kk) {
        const int ky = kk / 3, kx = kk % 3;

        __syncthreads();  // covers s_off init (iter 0) and prior-tap gemm reads of s_samp

        // ---- bilinear sampling: all 256 channels x 32 pixels for this tap ----
        #pragma unroll 4
        for (int cc = 0; cc < 32; ++cc) {
            const int c = crow * 32 + cc;
            const int g = c >> 6;                 // deform group = c / 64
            const float dy = s_off[g][kk][0][p];
            const float dx = s_off[g][kk][1][p];
            const float yc = (float)(h + ky - PAD_) + dy;
            const float xc = (float)(w0 + p + kx - PAD_) + dx;
            const float yf = floorf(yc), xf = floorf(xc);
            const float wy = yc - yf, wx = xc - xf;
            const int yi = (int)yf, xi = (int)xf;
            const float* xb = x + ((size_t)(b * CIN_ + c)) * (H_ * W_);
            const bool y0ok = (yi >= 0) && (yi < H_);
            const bool y1ok = (yi + 1 >= 0) && (yi + 1 < H_);
            const bool x0ok = (xi >= 0) && (xi < W_);
            const bool x1ok = (xi + 1 >= 0) && (xi + 1 < W_);
            float v00 = (y0ok && x0ok) ? xb[yi * W_ + xi]           : 0.f;
            float v01 = (y0ok && x1ok) ? xb[yi * W_ + xi + 1]       : 0.f;
            float v10 = (y1ok && x0ok) ? xb[(yi + 1) * W_ + xi]     : 0.f;
            float v11 = (y1ok && x1ok) ? xb[(yi + 1) * W_ + xi + 1] : 0.f;
            s_samp[c][p] = v00 * (1.f - wy) * (1.f - wx) + v01 * (1.f - wy) * wx
                         + v10 * wy * (1.f - wx)         + v11 * wy * wx;
        }

        // ---- GEMM: acc[o][p] += sum_c w[o][c][kk] * samp[c][p], c in chunks of 32 ----
        for (int cb = 0; cb < CIN_; cb += 32) {
            __syncthreads();  // sampling done (first chunk) / prior chunk done with s_w
            for (int i = tid; i < 32 * COUT_; i += 256) {
                ((float*)s_w)[i] = wT[(size_t)(kk * CIN_ + cb) * COUT_ + i];
            }
            __syncthreads();
            #pragma unroll 4
            for (int ci = 0; ci < 32; ++ci) {
                const float4 sv = *(const float4*)&s_samp[cb + ci][p0];
                const float4 wa = *(const float4*)&s_w[ci][o0];
                const float4 wb = *(const float4*)&s_w[ci][o0 + 4];
                const float wr[8]  = {wa.x, wa.y, wa.z, wa.w, wb.x, wb.y, wb.z, wb.w};
                const float svv[4] = {sv.x, sv.y, sv.z, sv.w};
                #pragma unroll
                for (int i = 0; i < 8; ++i)
                    #pragma unroll
                    for (int j = 0; j < 4; ++j)
                        acc[i][j] += wr[i] * svv[j];
            }
        }
    }

    // ---- epilogue: ReLU + coalesced float4 stores ----
    #pragma unroll
    for (int i = 0; i < 8; ++i) {
        float4 o4;
        o4.x = fmaxf(acc[i][0], 0.f);
        o4.y = fmaxf(acc[i][1], 0.f);
        o4.z = fmaxf(acc[i][2], 0.f);
        o4.w = fmaxf(acc[i][3], 0.f);
        *(float4*)&out[(((size_t)b * COUT_ + o0 + i) * H_ + h) * W_ + w0 + p0] = o4;
    }
}

extern "C" void kernel_launch(void* const* d_in, const int* in_sizes, int n_in,
                              void* d_out, int out_size, void* d_ws, size_t ws_size,
                              hipStream_t stream) {
    const float* x     = (const float*)d_in[0];
    const float* y     = (const float*)d_in[1];
    const float* w_off = (const float*)d_in[2];
    const float* w_def = (const float*)d_in[3];
    float* out = (float*)d_out;
    float* wT  = (float*)d_ws;   // KK_*CIN_*COUT_ floats = 2.36 MB

    const int nw = KK_ * CIN_ * COUT_;
    wt_kernel<<<(nw + 255) / 256, 256, 0, stream>>>(w_def, wT);

    dim3 grid(W_ / TP, H_, B_);
    dcn_kernel<<<grid, 256, 0, stream>>>(x, y, w_off, wT, out);
}

// Round 2
// 195.525 us; speedup vs baseline: 3.2826x; 3.2826x over previous
//
#include <hip/hip_runtime.h>
#include <cstddef>

#define B_    4
#define CIN_  256
#define COUT_ 256
#define H_    64
#define W_    64
#define KK_   9
#define G_    4
#define PAD_  1
#define TP    32          // pixels per block (32 px x 256 outs per block)
#define NSTEP 72          // 9 taps * 8 channel-chunks of 32

typedef short bf16x8 __attribute__((ext_vector_type(8)));
typedef float f32x4  __attribute__((ext_vector_type(4)));

typedef __attribute__((address_space(1))) const unsigned int* gptr_t;
typedef __attribute__((address_space(3))) unsigned int*       lptr_t;

// fp32 -> bf16 round-to-nearest-even (finite inputs)
__device__ __forceinline__ unsigned short f2bf(float v) {
    unsigned int u = __float_as_uint(v);
    u += 0x7fffu + ((u >> 16) & 1u);
    return (unsigned short)(u >> 16);
}

// wb[kk*8+cc][o][cl] (bf16) from w[o][c][kk] (fp32); each 16KB tile contiguous
// so the main kernel can stage it flat with global_load_lds (wave-uniform+lane*16).
__global__ __launch_bounds__(256) void wt_kernel(const float* __restrict__ w,
                                                 unsigned short* __restrict__ wb) {
    int idx = blockIdx.x * 256 + threadIdx.x;
    if (idx >= KK_ * CIN_ * COUT_) return;
    int cl   = idx & 31;
    int o    = (idx >> 5) & 255;
    int tile = idx >> 13;          // kk*8 + cc
    int kk   = tile >> 3;
    int cc   = tile & 7;
    int c    = cc * 32 + cl;
    wb[idx] = f2bf(w[(o * CIN_ + c) * KK_ + kk]);
}

__global__ __launch_bounds__(256, 2) void dcn_kernel(
    const float* __restrict__ x, const float* __restrict__ y,
    const float* __restrict__ w_off, const unsigned short* __restrict__ wb,
    float* __restrict__ out)
{
    __shared__ unsigned short s_S[TP][32];       // 2 KB  sampled tile [px][c]
    __shared__ unsigned short s_W[COUT_][32];    // 16 KB weight chunk [o][c]
    __shared__ float          s_off[72][TP];     // 9 KB  offsets [ch][px]

    const int tid  = threadIdx.x;
    const int b    = blockIdx.z;
    const int h    = blockIdx.y;
    const int w0   = blockIdx.x * TP;
    const int lane = tid & 63;
    const int wave = tid >> 6;

    // ---- offsets: s_off[ch][p] = y0*w_off[ch][0] + y1*w_off[ch][1], ch=(g*9+kk)*2+d ----
    for (int i = tid; i < 72 * TP; i += 256) {
        int p  = i & (TP - 1);
        int ch = i / TP;
        float yv0 = y[((b * 2 + 0) * H_ + h) * W_ + w0 + p];
        float yv1 = y[((b * 2 + 1) * H_ + h) * W_ + w0 + p];
        s_off[ch][p] = fmaf(yv0, w_off[ch * 2 + 0], yv1 * w_off[ch * 2 + 1]);
    }

    // sampling mapping: thread -> (pixel, 4 channels of the 32-chunk)
    const int sp = tid & (TP - 1);
    const int c0 = (tid >> 5) * 4;

    // mfma mapping: wave -> (pixel group of 16, COUT half of 128)
    const int nt  = wave & 1;
    const int mh  = wave >> 1;
    const int l15 = lane & 15;
    const int kq  = lane >> 4;

    f32x4 acc[8];
    #pragma unroll
    for (int i = 0; i < 8; ++i) acc[i] = (f32x4){0.f, 0.f, 0.f, 0.f};

    const unsigned short* s_W_flat = &s_W[0][0];

    for (int step = 0; step < NSTEP; ++step) {
        const int kk = step >> 3;
        const int cc = step & 7;
        const int g  = cc >> 1;          // deform group = (cc*32)/64

        __syncthreads();   // prior MFMA done with s_S/s_W (and s_off ready, step 0)

        // ---- stage W chunk: flat 16 KB, async global->LDS, 16 B/lane x 4 passes ----
        {
            const unsigned short* src = wb + (size_t)step * 8192;
            #pragma unroll
            for (int j = 0; j < 4; ++j) {
                const int off = (j * 256 + tid) * 8;  // ushort index, 16B per thread
                __builtin_amdgcn_global_load_lds((gptr_t)(src + off),
                                                 (lptr_t)(s_W_flat + off), 16, 0, 0);
            }
        }

        // ---- sample S chunk: 32 px x 32 ch, bilinear, masked weights ----
        {
            const int   chy = (g * KK_ + kk) * 2;
            const float dy  = s_off[chy][sp];
            const float dx  = s_off[chy + 1][sp];
            const float yc  = (float)(h + (kk / 3) - PAD_) + dy;
            const float xc  = (float)(w0 + sp + (kk % 3) - PAD_) + dx;
            const float yf  = floorf(yc), xf = floorf(xc);
            const float wy  = yc - yf,    wx = xc - xf;
            const int   yi  = (int)yf,    xi = (int)xf;
            float w00 = (1.f - wy) * (1.f - wx);
            float w01 = (1.f - wy) * wx;
            float w10 = wy * (1.f - wx);
            float w11 = wy * wx;
            const bool y0ok = (yi >= 0) & (yi < H_);
            const bool y1ok = (yi >= -1) & (yi < H_ - 1);
            const bool x0ok = (xi >= 0) & (xi < W_);
            const bool x1ok = (xi >= -1) & (xi < W_ - 1);
            w00 = (y0ok & x0ok) ? w00 : 0.f;
            w01 = (y0ok & x1ok) ? w01 : 0.f;
            w10 = (y1ok & x0ok) ? w10 : 0.f;
            w11 = (y1ok & x1ok) ? w11 : 0.f;
            const int y0c = min(max(yi, 0), H_ - 1);
            const int y1c = min(max(yi + 1, 0), H_ - 1);
            const int x0c = min(max(xi, 0), W_ - 1);
            const int x1c = min(max(xi + 1, 0), W_ - 1);
            const int a00 = y0c * W_ + x0c;
            const int a01 = y0c * W_ + x1c;
            const int a10 = y1c * W_ + x0c;
            const int a11 = y1c * W_ + x1c;
            const float* xb = x + ((size_t)b * CIN_ + cc * 32 + c0) * (H_ * W_);
            unsigned short t0, t1, t2, t3;
            {
                const float* xp = xb;
                t0 = f2bf(w00 * xp[a00] + w01 * xp[a01] + w10 * xp[a10] + w11 * xp[a11]);
                xp += H_ * W_;
                t1 = f2bf(w00 * xp[a00] + w01 * xp[a01] + w10 * xp[a10] + w11 * xp[a11]);
                xp += H_ * W_;
                t2 = f2bf(w00 * xp[a00] + w01 * xp[a01] + w10 * xp[a10] + w11 * xp[a11]);
                xp += H_ * W_;
                t3 = f2bf(w00 * xp[a00] + w01 * xp[a01] + w10 * xp[a10] + w11 * xp[a11]);
            }
            *(ushort4*)&s_S[sp][c0] = make_ushort4(t0, t1, t2, t3);
        }

        __syncthreads();   // sampling + W staging complete (compiler drains vmcnt)

        // ---- MFMA: wave covers [mh*128, +128) outs x [nt*16, +16) px, K=32 ----
        const bf16x8 bfrag = *(const bf16x8*)&s_S[nt * 16 + l15][kq * 8];
        #pragma unroll
        for (int mt = 0; mt < 8; ++mt) {
            const bf16x8 afrag = *(const bf16x8*)&s_W[mh * 128 + mt * 16 + l15][kq * 8];
            acc[mt] = __builtin_amdgcn_mfma_f32_16x16x32_bf16(afrag, bfrag, acc[mt], 0, 0, 0);
        }
    }

    // ---- epilogue: ReLU + store. C/D: col=lane&15 -> px, row=(lane>>4)*4+r -> o ----
    const int pxg = w0 + nt * 16 + l15;
    #pragma unroll
    for (int mt = 0; mt < 8; ++mt) {
        const int obase = mh * 128 + mt * 16 + kq * 4;
        #pragma unroll
        for (int r = 0; r < 4; ++r) {
            out[(((size_t)b * COUT_ + obase + r) * H_ + h) * W_ + pxg] =
                fmaxf(acc[mt][r], 0.f);
        }
    }
}

extern "C" void kernel_launch(void* const* d_in, const int* in_sizes, int n_in,
                              void* d_out, int out_size, void* d_ws, size_t ws_size,
                              hipStream_t stream) {
    const float* x     = (const float*)d_in[0];
    const float* y     = (const float*)d_in[1];
    const float* w_off = (const float*)d_in[2];
    const float* w_def = (const float*)d_in[3];
    float* out = (float*)d_out;
    unsigned short* wb = (unsigned short*)d_ws;   // 9*256*256 bf16 = 1.18 MB

    const int nw = KK_ * CIN_ * COUT_;
    wt_kernel<<<(nw + 255) / 256, 256, 0, stream>>>(w_def, wb);

    dim3 grid(W_ / TP, H_, B_);
    dcn_kernel<<<grid, 256, 0, stream>>>(x, y, w_off, wb, out);
}

// Round 3
// 137.871 us; speedup vs baseline: 4.6552x; 1.4182x over previous
//
#include <hip/hip_runtime.h>
#include <cstddef>

#define B_    4
#define CIN_  256
#define COUT_ 256
#define H_    64
#define W_    64
#define KK_   9
#define G_    4
#define PAD_  1
#define TP    32

typedef short bf16x8 __attribute__((ext_vector_type(8)));
typedef float f32x4  __attribute__((ext_vector_type(4)));
typedef __attribute__((address_space(1))) const unsigned int* gptr_t;
typedef __attribute__((address_space(3))) unsigned int*       lptr_t;

// fp32 -> bf16 round-to-nearest-even
__device__ __forceinline__ unsigned short f2bf(float v) {
    unsigned int u = __float_as_uint(v);
    u += 0x7fffu + ((u >> 16) & 1u);
    return (unsigned short)(u >> 16);
}
__device__ __forceinline__ float f_lo(unsigned int u) { return __uint_as_float(u << 16); }
__device__ __forceinline__ float f_hi(unsigned int u) { return __uint_as_float(u & 0xffff0000u); }

// xT[b][h][w][c] (bf16, NHWC) <- x[b][c][h][w] (fp32). Block: (b,h,chalf) = 128 ch x 64 w.
__global__ __launch_bounds__(256) void xt_kernel(const float* __restrict__ x,
                                                 unsigned short* __restrict__ xT) {
    __shared__ unsigned short s[128][66];
    const int tid   = threadIdx.x;
    const int bh    = blockIdx.x >> 1;          // b*64 + h
    const int chalf = blockIdx.x & 1;
    const size_t src_base = ((size_t)(bh >> 6) * CIN_ + chalf * 128) * (H_ * W_) + (bh & 63) * W_;
    #pragma unroll 4
    for (int k = 0; k < 32; ++k) {
        int i = k * 256 + tid;
        int c = i >> 6, w = i & 63;
        s[c][w] = f2bf(x[src_base + (size_t)c * (H_ * W_) + w]);
    }
    __syncthreads();
    #pragma unroll 4
    for (int k = 0; k < 16; ++k) {
        int j  = k * 256 + tid;
        int c2 = (j & 63) * 2, w = j >> 6;
        unsigned int lo = s[c2][w], hi = s[c2 + 1][w];
        *(unsigned int*)(xT + ((size_t)bh * 64 + w) * 256 + chalf * 128 + c2) = lo | (hi << 16);
    }
}

// wb: 36 tiles [g][kk] of [o][pos*8+e] bf16, pos = j ^ (o&7), c = g*64 + j*8 + e
// (XOR swizzle baked in so global_load_lds stays contiguous but LDS reads are conflict-free)
__global__ __launch_bounds__(256) void wt_kernel(const float* __restrict__ w,
                                                 unsigned short* __restrict__ wb) {
    int idx = blockIdx.x * 256 + threadIdx.x;    // 36*16384 exactly
    int e   = idx & 7;
    int pos = (idx >> 3) & 7;
    int o   = (idx >> 6) & 255;
    int t   = idx >> 14;                         // g*9 + kk
    int g   = t / 9, kk = t - g * 9;
    int j   = pos ^ (o & 7);
    int c   = g * 64 + j * 8 + e;
    wb[idx] = f2bf(w[(o * CIN_ + c) * KK_ + kk]);
}

__global__ __launch_bounds__(256, 2) void dcn_kernel(
    const unsigned short* __restrict__ xT, const float* __restrict__ y,
    const float* __restrict__ w_off, const unsigned short* __restrict__ wb,
    float* __restrict__ out)
{
    __shared__ unsigned short s_W[COUT_ * 64];   // 32 KB, rows swizzled via wb
    __shared__ unsigned short s_S[TP * 64];      // 4 KB, rows swizzled at write
    __shared__ float          s_off[72 * TP];    // 9 KB

    const int tid = threadIdx.x;
    // XCD swizzle: blocks resident on one XCD share b and a contiguous h range
    const int bid = blockIdx.x;
    const int xcd = bid & 7, loc = bid >> 3;
    const int b   = xcd >> 1;
    const int h   = (xcd & 1) * 32 + (loc >> 1);
    const int w0  = (loc & 1) * TP;

    // ---- offsets: s_off[ch*32+p], ch = (g*9+kk)*2+d ----
    for (int i = tid; i < 72 * TP; i += 256) {
        int p = i & 31, ch = i >> 5;
        float yv0 = y[((b * 2 + 0) * H_ + h) * W_ + w0 + p];
        float yv1 = y[((b * 2 + 1) * H_ + h) * W_ + w0 + p];
        s_off[i] = fmaf(yv0, w_off[ch * 2], yv1 * w_off[ch * 2 + 1]);
    }

    const int sp   = tid & 31;        // sampling: pixel
    const int c8   = tid >> 5;        // sampling: 8-ch chunk within the 64-ch group
    const int lane = tid & 63, wave = tid >> 6;
    const int nt   = wave & 1, mh = wave >> 1;
    const int l15  = lane & 15, kq = lane >> 4, sw = l15 & 7;

    f32x4 acc[8];
    #pragma unroll
    for (int i = 0; i < 8; ++i) acc[i] = (f32x4){0.f, 0.f, 0.f, 0.f};

    for (int g = 0; g < G_; ++g) {
        for (int kk = 0; kk < KK_; ++kk) {
            const int step = g * KK_ + kk;
            __syncthreads();   // prev MFMA done with s_W/s_S; s_off ready (iter 0)

            // ---- DMA W tile: 32 KB async global->LDS, 16 B/lane x 8 passes ----
            const unsigned short* src = wb + (size_t)step * 16384;
            #pragma unroll
            for (int j = 0; j < 8; ++j) {
                const int off = (j * 256 + tid) * 8;
                __builtin_amdgcn_global_load_lds((gptr_t)(src + off),
                                                 (lptr_t)(s_W + off), 16, 0, 0);
            }

            // ---- sample: 32 px x 64 ch from NHWC bf16, 16 B vector corner loads ----
            {
                const int   chy = step * 2;
                const float dy  = s_off[chy * 32 + sp];
                const float dx  = s_off[chy * 32 + 32 + sp];
                const float yc  = (float)(h + (kk / 3) - PAD_) + dy;
                const float xc  = (float)(w0 + sp + (kk % 3) - PAD_) + dx;
                const float yf  = floorf(yc), xf = floorf(xc);
                const float wy  = yc - yf,    wx = xc - xf;
                const int   yi  = (int)yf,    xi = (int)xf;
                float w00 = (1.f - wy) * (1.f - wx);
                float w01 = (1.f - wy) * wx;
                float w10 = wy * (1.f - wx);
                float w11 = wy * wx;
                const bool y0ok = (yi >= 0) & (yi < H_);
                const bool y1ok = (yi >= -1) & (yi < H_ - 1);
                const bool x0ok = (xi >= 0) & (xi < W_);
                const bool x1ok = (xi >= -1) & (xi < W_ - 1);
                w00 = (y0ok & x0ok) ? w00 : 0.f;
                w01 = (y0ok & x1ok) ? w01 : 0.f;
                w10 = (y1ok & x0ok) ? w10 : 0.f;
                w11 = (y1ok & x1ok) ? w11 : 0.f;
                const int y0c = min(max(yi, 0), H_ - 1);
                const int y1c = min(max(yi + 1, 0), H_ - 1);
                const int x0c = min(max(xi, 0), W_ - 1);
                const int x1c = min(max(xi + 1, 0), W_ - 1);
                const unsigned short* xb = xT + g * 64 + c8 * 8;
                const size_t bb = (size_t)b * (H_ * W_ * 256);
                const uint4 A = *(const uint4*)(xb + bb + ((size_t)y0c * W_ + x0c) * 256);
                const uint4 Bv= *(const uint4*)(xb + bb + ((size_t)y0c * W_ + x1c) * 256);
                const uint4 C = *(const uint4*)(xb + bb + ((size_t)y1c * W_ + x0c) * 256);
                const uint4 D = *(const uint4*)(xb + bb + ((size_t)y1c * W_ + x1c) * 256);
                const unsigned int av[4] = {A.x, A.y, A.z, A.w};
                const unsigned int bv[4] = {Bv.x, Bv.y, Bv.z, Bv.w};
                const unsigned int cv[4] = {C.x, C.y, C.z, C.w};
                const unsigned int dv[4] = {D.x, D.y, D.z, D.w};
                unsigned int res[4];
                #pragma unroll
                for (int q = 0; q < 4; ++q) {
                    float rl = w00 * f_lo(av[q]);
                    rl = fmaf(w01, f_lo(bv[q]), rl);
                    rl = fmaf(w10, f_lo(cv[q]), rl);
                    rl = fmaf(w11, f_lo(dv[q]), rl);
                    float rh = w00 * f_hi(av[q]);
                    rh = fmaf(w01, f_hi(bv[q]), rh);
                    rh = fmaf(w10, f_hi(cv[q]), rh);
                    rh = fmaf(w11, f_hi(dv[q]), rh);
                    // pack [bf16(rl), bf16(rh)] by truncation (1 inst)
                    res[q] = __builtin_amdgcn_perm(__float_as_uint(rh),
                                                   __float_as_uint(rl), 0x07060302u);
                }
                *(uint4*)(s_S + sp * 64 + ((c8 ^ (sp & 7)) * 8)) =
                    make_uint4(res[0], res[1], res[2], res[3]);
            }

            __syncthreads();   // drains DMA + LDS writes

            // ---- MFMA: wave = [mh*128,+128) outs x [nt*16,+16) px, K=64 ----
            const unsigned short* sSrow = s_S + (nt * 16 + l15) * 64;
            #pragma unroll
            for (int kh = 0; kh < 2; ++kh) {
                const int pos = ((kh * 4 + kq) ^ sw) * 8;
                const bf16x8 bfrag = *(const bf16x8*)(sSrow + pos);
                #pragma unroll
                for (int mt = 0; mt < 8; ++mt) {
                    const bf16x8 afrag =
                        *(const bf16x8*)(s_W + (mh * 128 + mt * 16 + l15) * 64 + pos);
                    acc[mt] = __builtin_amdgcn_mfma_f32_16x16x32_bf16(afrag, bfrag, acc[mt], 0, 0, 0);
                }
            }
        }
    }

    // ---- epilogue: ReLU + store. C/D: col=lane&15 -> px, row=(lane>>4)*4+r -> o ----
    const int pxg = w0 + nt * 16 + l15;
    #pragma unroll
    for (int mt = 0; mt < 8; ++mt) {
        const int obase = mh * 128 + mt * 16 + kq * 4;
        #pragma unroll
        for (int r = 0; r < 4; ++r) {
            out[(((size_t)b * COUT_ + obase + r) * H_ + h) * W_ + pxg] =
                fmaxf(acc[mt][r], 0.f);
        }
    }
}

extern "C" void kernel_launch(void* const* d_in, const int* in_sizes, int n_in,
                              void* d_out, int out_size, void* d_ws, size_t ws_size,
                              hipStream_t stream) {
    const float* x     = (const float*)d_in[0];
    const float* y     = (const float*)d_in[1];
    const float* w_off = (const float*)d_in[2];
    const float* w_def = (const float*)d_in[3];
    float* out = (float*)d_out;

    unsigned short* xT = (unsigned short*)d_ws;                 // 4,194,304 bf16 = 8 MB
    unsigned short* wb = (unsigned short*)d_ws + 4194304;       // 589,824 bf16 = 1.18 MB

    xt_kernel<<<B_ * H_ * 2, 256, 0, stream>>>(x, xT);
    wt_kernel<<<(KK_ * G_ * 64 * COUT_ * 8) / 256 / 8, 256, 0, stream>>>(w_def, wb);
    dcn_kernel<<<512, 256, 0, stream>>>(xT, y, w_off, wb, out);
}